// Round 1
// baseline (871.283 us; speedup 1.0000x reference)
//
#include <hip/hip_runtime.h>
#include <stdint.h>

// ============================================================================
// MoE adapter layer, sparse top-2 dispatch, bf16 MFMA expert GEMMs.
// Workspace budget ~224 MiB (Abf16 64M + Bbf16 64M + xg 18M + h 73M + misc).
// Gating kept entirely fp32 (top-k decision boundaries are flip-sensitive).
// ============================================================================

typedef __attribute__((ext_vector_type(4))) float floatx4;
typedef __attribute__((ext_vector_type(8))) short shortx8;
typedef unsigned short ushort_t;

#define T_TOKENS 4096
#define D_DIM    1024
#define E_EXP    8
#define H_DIM    4096
#define P_DIM    256
#define ROWS_PAD 9344   // 8192 rows + per-expert 128-padding (max 9208) + slack
#define MBLK     73     // ROWS_PAD / 128

__device__ __forceinline__ ushort_t f2bf(float f) {
  union { float f; unsigned int u; } c; c.f = f;
  unsigned int u = c.u;
  unsigned int r = u + 0x7FFFu + ((u >> 16) & 1u);  // RNE
  return (ushort_t)(r >> 16);
}

// async global->LDS, 16B per lane; LDS dest = wave-uniform base + lane*16
__device__ __forceinline__ void stage16(const ushort_t* g, ushort_t* l) {
  __builtin_amdgcn_global_load_lds(
      (__attribute__((address_space(1))) void*)(uintptr_t)g,
      (__attribute__((address_space(3))) void*)l, 16, 0, 0);
}

// ---------------------------------------------------------------- convert
__global__ __launch_bounds__(256) void k_cvt(const float* __restrict__ src,
                                             ushort_t* __restrict__ dst, int n4) {
  int g = blockIdx.x * 256 + threadIdx.x;
  if (g >= n4) return;
  floatx4 v = ((const floatx4*)src)[g];
  ushort4 o; o.x = f2bf(v.x); o.y = f2bf(v.y); o.z = f2bf(v.z); o.w = f2bf(v.w);
  ((ushort4*)dst)[g] = o;
}

// ---------------------------------------------------------------- small init
__global__ __launch_bounds__(256) void k_small_init(int* counts, int* cursor,
                                                    float* frac_sum, int* row2tok) {
  int g = blockIdx.x * 256 + threadIdx.x;
  if (g < 8) { counts[g] = 0; cursor[g] = 0; frac_sum[g] = 0.f; }
  if (g < ROWS_PAD) row2tok[g] = -1;
}

// ---------------------------------------------------------------- proj = x @ Wp^T + bp   (fp32, 4-slot split accumulation)
// 256 blocks x 256 thr; block = 16 tokens x 256 cols; thread: 2 tok x 8 strided cols.
__global__ __launch_bounds__(256) void k_proj(const float* __restrict__ x,
                                              const float* __restrict__ Wp,
                                              const float* __restrict__ bp,
                                              float* __restrict__ proj) {
  __shared__ float Wc[256 * 36];   // chunk: 256 rows x 32 k, stride 36 (4-way max conflict)
  __shared__ float Xc[16 * 36];
  int tid = threadIdx.x;
  int t0 = blockIdx.x * 16;
  int cg = tid & 31, tg = tid >> 5;   // tg 0..7
  floatx4 acc[2][8];
#pragma unroll
  for (int a = 0; a < 2; a++)
#pragma unroll
    for (int b = 0; b < 8; b++) acc[a][b] = (floatx4){0.f, 0.f, 0.f, 0.f};
  for (int kc = 0; kc < 32; ++kc) {
    int k0 = kc * 32;
    __syncthreads();
#pragma unroll
    for (int it = 0; it < 8; ++it) {        // Wp chunk: 2048 float4
      int f = it * 256 + tid;
      int j = f >> 3, kk = (f & 7) << 2;
      floatx4 v = *(const floatx4*)(Wp + j * 1024 + k0 + kk);
      *(floatx4*)(Wc + j * 36 + kk) = v;
    }
    if (tid < 128) {                        // x chunk: 128 float4
      int t = tid >> 3, kk = (tid & 7) << 2;
      floatx4 v = *(const floatx4*)(x + (size_t)(t0 + t) * 1024 + k0 + kk);
      *(floatx4*)(Xc + t * 36 + kk) = v;
    }
    __syncthreads();
#pragma unroll
    for (int k4 = 0; k4 < 8; ++k4) {
      floatx4 xv[2], wv[8];
#pragma unroll
      for (int tt = 0; tt < 2; tt++) xv[tt] = *(floatx4*)(Xc + (tg * 2 + tt) * 36 + k4 * 4);
#pragma unroll
      for (int jj = 0; jj < 8; jj++) wv[jj] = *(floatx4*)(Wc + (cg + jj * 32) * 36 + k4 * 4);
#pragma unroll
      for (int tt = 0; tt < 2; tt++)
#pragma unroll
        for (int jj = 0; jj < 8; jj++) acc[tt][jj] += xv[tt] * wv[jj];
    }
  }
#pragma unroll
  for (int tt = 0; tt < 2; tt++)
#pragma unroll
    for (int jj = 0; jj < 8; jj++) {
      floatx4 a = acc[tt][jj];
      float s = (a.x + a.y) + (a.z + a.w);
      int t = t0 + tg * 2 + tt, j = cg + jj * 32;
      proj[t * 256 + j] = s + bp[j];
    }
}

// ---------------------------------------------------------------- gate: norm, logits, softmax, top-2, stats
__global__ __launch_bounds__(128) void k_gate(const float* __restrict__ proj,
                                              const float* __restrict__ sim,
                                              const float* __restrict__ temp,
                                              int* __restrict__ topi, float* __restrict__ wslot,
                                              float* __restrict__ swsum,
                                              float* __restrict__ frac_sum, int* __restrict__ counts) {
  __shared__ float simT[8][256];
  __shared__ float snorm[8];
  __shared__ float fracs[8];
  __shared__ int cnts[8];
  int tid = threadIdx.x;
  for (int i = tid; i < 2048; i += 128) { int p = i >> 3, e = i & 7; simT[e][p] = sim[i]; }
  if (tid < 8) { fracs[tid] = 0.f; cnts[tid] = 0; }
  __syncthreads();
  if (tid < 8) {
    float s = 0.f;
    for (int p = 0; p < 256; p++) { float v = simT[tid][p]; s += v * v; }
    snorm[tid] = fmaxf(sqrtf(s), 1e-12f);
  }
  __syncthreads();
  int t = blockIdx.x * 128 + tid;
  floatx4 n4 = (floatx4){0.f, 0.f, 0.f, 0.f};
  floatx4 d4[8];
#pragma unroll
  for (int e = 0; e < 8; e++) d4[e] = (floatx4){0.f, 0.f, 0.f, 0.f};
  const floatx4* pr = (const floatx4*)(proj + t * 256);
  for (int k4 = 0; k4 < 64; ++k4) {
    floatx4 p = pr[k4];
    n4 += p * p;
#pragma unroll
    for (int e = 0; e < 8; e++) d4[e] += p * *(const floatx4*)(&simT[e][k4 * 4]);
  }
  float nrm = fmaxf(sqrtf((n4.x + n4.y) + (n4.z + n4.w)), 1e-12f);
  float scale = expf(fminf(temp[0], 4.6051701859880914f));  // log(100)
  float pe[8];
  float mx = -1e30f;
#pragma unroll
  for (int e = 0; e < 8; e++) {
    float d = (d4[e].x + d4[e].y) + (d4[e].z + d4[e].w);
    pe[e] = d / (nrm * snorm[e]) * scale;
    mx = fmaxf(mx, pe[e]);
  }
  float sum = 0.f;
#pragma unroll
  for (int e = 0; e < 8; e++) { pe[e] = expf(pe[e] - mx); sum += pe[e]; }
#pragma unroll
  for (int e = 0; e < 8; e++) pe[e] /= sum;
  int i0 = 0;
#pragma unroll
  for (int e = 1; e < 8; e++) if (pe[e] > pe[i0]) i0 = e;   // strict > : lowest idx on tie
  int i1 = (i0 == 0) ? 1 : 0;
#pragma unroll
  for (int e = 0; e < 8; e++) if (e != i1 && e != i0 && pe[e] > pe[i1]) i1 = e;
  float v0 = pe[i0], v1 = pe[i1];
  float s2 = v0 + v1 + 1e-8f;
  float w0 = v0 / s2, w1 = v1 / s2;
  topi[t * 2] = i0; topi[t * 2 + 1] = i1;
  wslot[t * 2] = w0; wslot[t * 2 + 1] = w1;
  swsum[t] = w0 + w1;
#pragma unroll
  for (int e = 0; e < 8; e++) atomicAdd(&fracs[e], pe[e]);
  atomicAdd(&cnts[i0], 1); atomicAdd(&cnts[i1], 1);
  __syncthreads();
  if (tid < 8) { atomicAdd(&frac_sum[tid], fracs[tid]); atomicAdd(&counts[tid], cnts[tid]); }
}

// ---------------------------------------------------------------- scan: padded offsets, block->expert table, tail outputs
__global__ void k_scan(const int* __restrict__ counts, const float* __restrict__ frac_sum,
                       int* __restrict__ offsets, int* __restrict__ blk2e,
                       float* __restrict__ out_tail) {
  __shared__ int offs[9];
  if (threadIdx.x == 0) {
    int off = 0;
    for (int e = 0; e < 8; e++) { offs[e] = off; off += ((counts[e] + 127) >> 7) << 7; }
    offs[8] = off;
    for (int e = 0; e < 9; e++) offsets[e] = offs[e];
    float aux = 0.f;
    for (int e = 0; e < 8; e++) { float fr = frac_sum[e] / 4096.f; aux += (fr - 0.125f) * (fr - 0.125f); }
    out_tail[0] = aux;
  }
  __syncthreads();
  int tid = threadIdx.x;
  if (tid < MBLK) {
    int r = tid * 128, e = -1;
    for (int q = 0; q < 8; q++) if (r >= offs[q] && r < offs[q + 1]) e = q;
    blk2e[tid] = e;
  }
  if (tid < 8) {
    out_tail[1 + tid] = frac_sum[tid] / 4096.f;
    out_tail[9 + tid] = (float)counts[tid];
  }
}

// ---------------------------------------------------------------- assign rows
__global__ __launch_bounds__(256) void k_assign(const int* __restrict__ topi,
                                                const float* __restrict__ wslot,
                                                const int* __restrict__ offsets,
                                                int* __restrict__ cursor,
                                                int* __restrict__ row2tok, float* __restrict__ roww) {
  int g = blockIdx.x * 256 + threadIdx.x;
  if (g >= 8192) return;
  int t = g >> 1;
  int e = topi[g];
  int pos = atomicAdd(&cursor[e], 1);
  int r = offsets[e] + pos;
  row2tok[r] = t;
  roww[r] = wslot[g];
}

// ---------------------------------------------------------------- gather x rows -> bf16 (zeros for pad rows)
__global__ __launch_bounds__(64) void k_gather(const float* __restrict__ x,
                                               const int* __restrict__ row2tok,
                                               ushort_t* __restrict__ xg) {
  int r = blockIdx.x;
  int t = row2tok[r];
  ushort4* dst = (ushort4*)(xg + (size_t)r * 1024);
  if (t < 0) {
    ushort4 z; z.x = z.y = z.z = z.w = 0;
    for (int i = threadIdx.x; i < 256; i += 64) dst[i] = z;
  } else {
    const floatx4* src = (const floatx4*)(x + (size_t)t * 1024);
    for (int i = threadIdx.x; i < 256; i += 64) {
      floatx4 v = src[i];
      ushort4 o; o.x = f2bf(v.x); o.y = f2bf(v.y); o.z = f2bf(v.z); o.w = f2bf(v.w);
      dst[i] = o;
    }
  }
}

// ---------------------------------------------------------------- out = (w0+w1) * x
__global__ __launch_bounds__(256) void k_init_out(const float* __restrict__ x,
                                                  const float* __restrict__ swsum,
                                                  float* __restrict__ out) {
  int g = blockIdx.x * 256 + threadIdx.x;   // float4 index, 1,048,576 total
  float s = swsum[g >> 8];
  floatx4 v = ((const floatx4*)x)[g];
  ((floatx4*)out)[g] = v * s;
}

// ---------------------------------------------------------------- bf16 MFMA GEMM (NT), m97-style 128x128 tile
// mode 1 (hout!=0): h = Aop @ W^T + bias -> bf16
// mode 2 (hout==0): f = Aop @ W^T + bias; atomicAdd(out[tok], roww*f)
__global__ __launch_bounds__(256) void k_gemm(const ushort_t* __restrict__ Aop0,
                                              const ushort_t* __restrict__ Wall,
                                              const float* __restrict__ bias,
                                              const int* __restrict__ blk2e,
                                              int K, int N,
                                              ushort_t* __restrict__ hout,
                                              float* __restrict__ outp,
                                              const int* __restrict__ row2tok,
                                              const float* __restrict__ roww) {
  int e = blk2e[blockIdx.y];
  if (e < 0) return;
  int rb = blockIdx.y, nb = blockIdx.x;
  const ushort_t* Aop = Aop0 + (size_t)rb * 128 * K;
  const ushort_t* Bop = Wall + (size_t)e * N * K + (size_t)nb * 128 * K;
  __shared__ ushort_t As[4096], Bs[4096];   // 128 x 32 bf16 each
  int tid = threadIdx.x, lane = tid & 63, wv = tid >> 6;
  int l15 = lane & 15, q = lane >> 4;
  int wm = (wv & 1) << 6, wn = (wv >> 1) << 6;
  floatx4 acc[4][4];
#pragma unroll
  for (int i = 0; i < 4; i++)
#pragma unroll
    for (int j = 0; j < 4; j++) acc[i][j] = (floatx4){0.f, 0.f, 0.f, 0.f};
  int c0 = tid, c1 = 256 + tid;
  size_t sa0 = (size_t)(c0 >> 2) * K + ((c0 & 3) << 3);
  size_t sa1 = (size_t)(c1 >> 2) * K + ((c1 & 3) << 3);
  ushort_t* lA0 = As + wv * 512;
  ushort_t* lA1 = As + 2048 + wv * 512;
  ushort_t* lB0 = Bs + wv * 512;
  ushort_t* lB1 = Bs + 2048 + wv * 512;
  int ksteps = K >> 5;
  for (int ks = 0; ks < ksteps; ++ks) {
    const ushort_t* Ak = Aop + ks * 32;
    const ushort_t* Bk = Bop + ks * 32;
    stage16(Ak + sa0, lA0);
    stage16(Ak + sa1, lA1);
    stage16(Bk + sa0, lB0);
    stage16(Bk + sa1, lB1);
    __syncthreads();   // drains vmcnt (global_load_lds) + barrier
    shortx8 af[4], bfv[4];
#pragma unroll
    for (int i = 0; i < 4; i++) af[i] = *(const shortx8*)(As + ((wm + i * 16 + l15) << 5) + (q << 3));
#pragma unroll
    for (int i = 0; i < 4; i++) bfv[i] = *(const shortx8*)(Bs + ((wn + i * 16 + l15) << 5) + (q << 3));
#pragma unroll
    for (int i = 0; i < 4; i++)
#pragma unroll
      for (int j = 0; j < 4; j++)
        acc[i][j] = __builtin_amdgcn_mfma_f32_16x16x32_bf16(af[i], bfv[j], acc[i][j], 0, 0, 0);
    __syncthreads();
  }
  const float* be = bias + (size_t)e * N + (size_t)nb * 128;
  if (hout) {
    ushort_t* hp = hout + (size_t)(rb * 128) * N + nb * 128;
#pragma unroll
    for (int j = 0; j < 4; j++) {
      int n = wn + j * 16 + l15;
      float bv = be[n];
#pragma unroll
      for (int i = 0; i < 4; i++)
#pragma unroll
        for (int r = 0; r < 4; r++) {
          int m = wm + i * 16 + (q << 2) + r;          // D row = quad*4 + reg
          hp[(size_t)m * N + n] = f2bf(acc[i][j][r] + bv);
        }
    }
  } else {
#pragma unroll
    for (int j = 0; j < 4; j++) {
      int n = wn + j * 16 + l15;
      float bv = be[n];
#pragma unroll
      for (int i = 0; i < 4; i++)
#pragma unroll
        for (int r = 0; r < 4; r++) {
          int m = wm + i * 16 + (q << 2) + r;
          int grow = rb * 128 + m;
          int tok = row2tok[grow];
          if (tok >= 0) {
            float v = (acc[i][j][r] + bv) * roww[grow];
            atomicAdd(outp + (size_t)tok * 1024 + nb * 128 + n, v);
          }
        }
    }
  }
}

// ============================================================================
extern "C" void kernel_launch(void* const* d_in, const int* in_sizes, int n_in,
                              void* d_out, int out_size, void* d_ws, size_t ws_size,
                              hipStream_t stream) {
  (void)in_sizes; (void)n_in; (void)out_size; (void)ws_size;
  const float* x      = (const float*)d_in[0];
  const float* Wp     = (const float*)d_in[1];
  const float* bp     = (const float*)d_in[2];
  const float* sim    = (const float*)d_in[3];
  const float* temp   = (const float*)d_in[4];
  const float* A      = (const float*)d_in[5];
  const float* a_bias = (const float*)d_in[6];
  const float* Bw     = (const float*)d_in[7];
  const float* b_bias = (const float*)d_in[8];
  float* out = (float*)d_out;

  char* ws = (char*)d_ws;
  ushort_t* Abf    = (ushort_t*)(ws);                     //  67,108,864 B
  ushort_t* Bbf    = (ushort_t*)(ws + 67108864);          //  67,108,864 B
  ushort_t* xg     = (ushort_t*)(ws + 134217728);         //  19,136,512 B
  ushort_t* h      = (ushort_t*)(ws + 153354240);         //  76,546,048 B
  float*    proj   = (float*)   (ws + 229900288);         //   4,194,304 B
  int*      topi   = (int*)     (ws + 234094592);
  float*    wslot  = (float*)   (ws + 234127360);
  float*    swsum  = (float*)   (ws + 234160128);
  int*      row2tok= (int*)     (ws + 234176512);
  float*    roww   = (float*)   (ws + 234213888);
  int*      counts = (int*)     (ws + 234251264);
  int*      cursor = (int*)     (ws + 234251296);
  int*      offsets= (int*)     (ws + 234251328);
  int*      blk2e  = (int*)     (ws + 234251392);
  float*    fracs  = (float*)   (ws + 234251712);
  // total ws use ~234.3 MB

  k_cvt<<<32768, 256, 0, stream>>>(A,  Abf, 8388608);
  k_cvt<<<32768, 256, 0, stream>>>(Bw, Bbf, 8388608);
  k_small_init<<<37, 256, 0, stream>>>(counts, cursor, fracs, row2tok);
  k_proj<<<256, 256, 0, stream>>>(x, Wp, bp, proj);
  k_gate<<<32, 128, 0, stream>>>(proj, sim, temp, topi, wslot, swsum, fracs, counts);
  k_scan<<<1, 128, 0, stream>>>(counts, fracs, offsets, blk2e, out + 4194304);
  k_assign<<<32, 256, 0, stream>>>(topi, wslot, offsets, cursor, row2tok, roww);
  k_gather<<<ROWS_PAD, 64, 0, stream>>>(x, row2tok, xg);
  k_init_out<<<4096, 256, 0, stream>>>(x, swsum, out);
  // GEMM1: h[r][j] = xg[r] . A_e[j] + a_bias  (K=1024, N=4096)
  k_gemm<<<dim3(32, MBLK), 256, 0, stream>>>(xg, Abf, a_bias, blk2e, 1024, 4096,
                                             h, nullptr, nullptr, nullptr);
  // GEMM2: f[r][i] = h[r] . B_e[i] + b_bias; out[tok] += roww * f  (K=4096, N=1024)
  k_gemm<<<dim3(8, MBLK), 256, 0, stream>>>(h, Bbf, b_bias, blk2e, 4096, 1024,
                                            nullptr, out, row2tok, roww);
}

// Round 2
// 857.358 us; speedup vs baseline: 1.0162x; 1.0162x over previous
//
#include <hip/hip_runtime.h>
#include <stdint.h>

// ============================================================================
// MoE adapter layer, sparse top-2 dispatch, bf16 MFMA expert GEMMs.
// R1: BK=64 K-loop (32 MFMA per barrier pair, XOR-swizzled LDS chunks),
//     split-K x4 for GEMM2 (584 -> 2336 blocks; fixes 2.3 blocks/CU latency
//     exposure seen as MfmaUtil 10.7% / Occupancy 14%).
// Gating kept entirely fp32 (top-k decision boundaries are flip-sensitive).
// ============================================================================

typedef __attribute__((ext_vector_type(4))) float floatx4;
typedef __attribute__((ext_vector_type(8))) short shortx8;
typedef unsigned short ushort_t;

#define T_TOKENS 4096
#define D_DIM    1024
#define E_EXP    8
#define H_DIM    4096
#define P_DIM    256
#define ROWS_PAD 9344   // 8192 rows + per-expert 128-padding (max 9208) + slack
#define MBLK     73     // ROWS_PAD / 128

__device__ __forceinline__ ushort_t f2bf(float f) {
  union { float f; unsigned int u; } c; c.f = f;
  unsigned int u = c.u;
  unsigned int r = u + 0x7FFFu + ((u >> 16) & 1u);  // RNE
  return (ushort_t)(r >> 16);
}

// async global->LDS, 16B per lane; LDS dest = wave-uniform base + lane*16
__device__ __forceinline__ void stage16(const ushort_t* g, ushort_t* l) {
  __builtin_amdgcn_global_load_lds(
      (__attribute__((address_space(1))) void*)(uintptr_t)g,
      (__attribute__((address_space(3))) void*)l, 16, 0, 0);
}

// ---------------------------------------------------------------- convert
__global__ __launch_bounds__(256) void k_cvt(const float* __restrict__ src,
                                             ushort_t* __restrict__ dst, int n4) {
  int g = blockIdx.x * 256 + threadIdx.x;
  if (g >= n4) return;
  floatx4 v = ((const floatx4*)src)[g];
  ushort4 o; o.x = f2bf(v.x); o.y = f2bf(v.y); o.z = f2bf(v.z); o.w = f2bf(v.w);
  ((ushort4*)dst)[g] = o;
}

// ---------------------------------------------------------------- small init
__global__ __launch_bounds__(256) void k_small_init(int* counts, int* cursor,
                                                    float* frac_sum, int* row2tok) {
  int g = blockIdx.x * 256 + threadIdx.x;
  if (g < 8) { counts[g] = 0; cursor[g] = 0; frac_sum[g] = 0.f; }
  if (g < ROWS_PAD) row2tok[g] = -1;
}

// ---------------------------------------------------------------- proj = x @ Wp^T + bp   (fp32)
__global__ __launch_bounds__(256) void k_proj(const float* __restrict__ x,
                                              const float* __restrict__ Wp,
                                              const float* __restrict__ bp,
                                              float* __restrict__ proj) {
  __shared__ float Wc[256 * 36];
  __shared__ float Xc[16 * 36];
  int tid = threadIdx.x;
  int t0 = blockIdx.x * 16;
  int cg = tid & 31, tg = tid >> 5;
  floatx4 acc[2][8];
#pragma unroll
  for (int a = 0; a < 2; a++)
#pragma unroll
    for (int b = 0; b < 8; b++) acc[a][b] = (floatx4){0.f, 0.f, 0.f, 0.f};
  for (int kc = 0; kc < 32; ++kc) {
    int k0 = kc * 32;
    __syncthreads();
#pragma unroll
    for (int it = 0; it < 8; ++it) {
      int f = it * 256 + tid;
      int j = f >> 3, kk = (f & 7) << 2;
      floatx4 v = *(const floatx4*)(Wp + j * 1024 + k0 + kk);
      *(floatx4*)(Wc + j * 36 + kk) = v;
    }
    if (tid < 128) {
      int t = tid >> 3, kk = (tid & 7) << 2;
      floatx4 v = *(const floatx4*)(x + (size_t)(t0 + t) * 1024 + k0 + kk);
      *(floatx4*)(Xc + t * 36 + kk) = v;
    }
    __syncthreads();
#pragma unroll
    for (int k4 = 0; k4 < 8; ++k4) {
      floatx4 xv[2], wv[8];
#pragma unroll
      for (int tt = 0; tt < 2; tt++) xv[tt] = *(floatx4*)(Xc + (tg * 2 + tt) * 36 + k4 * 4);
#pragma unroll
      for (int jj = 0; jj < 8; jj++) wv[jj] = *(floatx4*)(Wc + (cg + jj * 32) * 36 + k4 * 4);
#pragma unroll
      for (int tt = 0; tt < 2; tt++)
#pragma unroll
        for (int jj = 0; jj < 8; jj++) acc[tt][jj] += xv[tt] * wv[jj];
    }
  }
#pragma unroll
  for (int tt = 0; tt < 2; tt++)
#pragma unroll
    for (int jj = 0; jj < 8; jj++) {
      floatx4 a = acc[tt][jj];
      float s = (a.x + a.y) + (a.z + a.w);
      int t = t0 + tg * 2 + tt, j = cg + jj * 32;
      proj[t * 256 + j] = s + bp[j];
    }
}

// ---------------------------------------------------------------- gate
__global__ __launch_bounds__(128) void k_gate(const float* __restrict__ proj,
                                              const float* __restrict__ sim,
                                              const float* __restrict__ temp,
                                              int* __restrict__ topi, float* __restrict__ wslot,
                                              float* __restrict__ swsum,
                                              float* __restrict__ frac_sum, int* __restrict__ counts) {
  __shared__ float simT[8][256];
  __shared__ float snorm[8];
  __shared__ float fracs[8];
  __shared__ int cnts[8];
  int tid = threadIdx.x;
  for (int i = tid; i < 2048; i += 128) { int p = i >> 3, e = i & 7; simT[e][p] = sim[i]; }
  if (tid < 8) { fracs[tid] = 0.f; cnts[tid] = 0; }
  __syncthreads();
  if (tid < 8) {
    float s = 0.f;
    for (int p = 0; p < 256; p++) { float v = simT[tid][p]; s += v * v; }
    snorm[tid] = fmaxf(sqrtf(s), 1e-12f);
  }
  __syncthreads();
  int t = blockIdx.x * 128 + tid;
  floatx4 n4 = (floatx4){0.f, 0.f, 0.f, 0.f};
  floatx4 d4[8];
#pragma unroll
  for (int e = 0; e < 8; e++) d4[e] = (floatx4){0.f, 0.f, 0.f, 0.f};
  const floatx4* pr = (const floatx4*)(proj + t * 256);
  for (int k4 = 0; k4 < 64; ++k4) {
    floatx4 p = pr[k4];
    n4 += p * p;
#pragma unroll
    for (int e = 0; e < 8; e++) d4[e] += p * *(const floatx4*)(&simT[e][k4 * 4]);
  }
  float nrm = fmaxf(sqrtf((n4.x + n4.y) + (n4.z + n4.w)), 1e-12f);
  float scale = expf(fminf(temp[0], 4.6051701859880914f));  // log(100)
  float pe[8];
  float mx = -1e30f;
#pragma unroll
  for (int e = 0; e < 8; e++) {
    float d = (d4[e].x + d4[e].y) + (d4[e].z + d4[e].w);
    pe[e] = d / (nrm * snorm[e]) * scale;
    mx = fmaxf(mx, pe[e]);
  }
  float sum = 0.f;
#pragma unroll
  for (int e = 0; e < 8; e++) { pe[e] = expf(pe[e] - mx); sum += pe[e]; }
#pragma unroll
  for (int e = 0; e < 8; e++) pe[e] /= sum;
  int i0 = 0;
#pragma unroll
  for (int e = 1; e < 8; e++) if (pe[e] > pe[i0]) i0 = e;
  int i1 = (i0 == 0) ? 1 : 0;
#pragma unroll
  for (int e = 0; e < 8; e++) if (e != i1 && e != i0 && pe[e] > pe[i1]) i1 = e;
  float v0 = pe[i0], v1 = pe[i1];
  float s2 = v0 + v1 + 1e-8f;
  float w0 = v0 / s2, w1 = v1 / s2;
  topi[t * 2] = i0; topi[t * 2 + 1] = i1;
  wslot[t * 2] = w0; wslot[t * 2 + 1] = w1;
  swsum[t] = w0 + w1;
#pragma unroll
  for (int e = 0; e < 8; e++) atomicAdd(&fracs[e], pe[e]);
  atomicAdd(&cnts[i0], 1); atomicAdd(&cnts[i1], 1);
  __syncthreads();
  if (tid < 8) { atomicAdd(&frac_sum[tid], fracs[tid]); atomicAdd(&counts[tid], cnts[tid]); }
}

// ---------------------------------------------------------------- scan
__global__ void k_scan(const int* __restrict__ counts, const float* __restrict__ frac_sum,
                       int* __restrict__ offsets, int* __restrict__ blk2e,
                       float* __restrict__ out_tail) {
  __shared__ int offs[9];
  if (threadIdx.x == 0) {
    int off = 0;
    for (int e = 0; e < 8; e++) { offs[e] = off; off += ((counts[e] + 127) >> 7) << 7; }
    offs[8] = off;
    for (int e = 0; e < 9; e++) offsets[e] = offs[e];
    float aux = 0.f;
    for (int e = 0; e < 8; e++) { float fr = frac_sum[e] / 4096.f; aux += (fr - 0.125f) * (fr - 0.125f); }
    out_tail[0] = aux;
  }
  __syncthreads();
  int tid = threadIdx.x;
  if (tid < MBLK) {
    int r = tid * 128, e = -1;
    for (int q = 0; q < 8; q++) if (r >= offs[q] && r < offs[q + 1]) e = q;
    blk2e[tid] = e;
  }
  if (tid < 8) {
    out_tail[1 + tid] = frac_sum[tid] / 4096.f;
    out_tail[9 + tid] = (float)counts[tid];
  }
}

// ---------------------------------------------------------------- assign rows
__global__ __launch_bounds__(256) void k_assign(const int* __restrict__ topi,
                                                const float* __restrict__ wslot,
                                                const int* __restrict__ offsets,
                                                int* __restrict__ cursor,
                                                int* __restrict__ row2tok, float* __restrict__ roww) {
  int g = blockIdx.x * 256 + threadIdx.x;
  if (g >= 8192) return;
  int t = g >> 1;
  int e = topi[g];
  int pos = atomicAdd(&cursor[e], 1);
  int r = offsets[e] + pos;
  row2tok[r] = t;
  roww[r] = wslot[g];
}

// ---------------------------------------------------------------- gather x rows -> bf16
__global__ __launch_bounds__(64) void k_gather(const float* __restrict__ x,
                                               const int* __restrict__ row2tok,
                                               ushort_t* __restrict__ xg) {
  int r = blockIdx.x;
  int t = row2tok[r];
  ushort4* dst = (ushort4*)(xg + (size_t)r * 1024);
  if (t < 0) {
    ushort4 z; z.x = z.y = z.z = z.w = 0;
    for (int i = threadIdx.x; i < 256; i += 64) dst[i] = z;
  } else {
    const floatx4* src = (const floatx4*)(x + (size_t)t * 1024);
    for (int i = threadIdx.x; i < 256; i += 64) {
      floatx4 v = src[i];
      ushort4 o; o.x = f2bf(v.x); o.y = f2bf(v.y); o.z = f2bf(v.z); o.w = f2bf(v.w);
      dst[i] = o;
    }
  }
}

// ---------------------------------------------------------------- out = (w0+w1) * x
__global__ __launch_bounds__(256) void k_init_out(const float* __restrict__ x,
                                                  const float* __restrict__ swsum,
                                                  float* __restrict__ out) {
  int g = blockIdx.x * 256 + threadIdx.x;
  float s = swsum[g >> 8];
  floatx4 v = ((const floatx4*)x)[g];
  ((floatx4*)out)[g] = v * s;
}

// ---------------------------------------------------------------- bf16 MFMA GEMM (NT), 128x128 tile, BK=64
// LDS layout: As/Bs 128 rows x 64 cols bf16, stored as 16B chunks with
// chunk' = chunk ^ (row & 7)  (kills the 16-way bank clash of 128B row stride;
// DMA writes stay lane-contiguous, we permute the *global* source instead).
// mode 1 (hout!=0): h = Aop @ W^T + bias -> bf16
// mode 2 (hout==0): f = Aop @ W^T (+bias iff z==0); atomicAdd(out[tok], roww*f)
__global__ __launch_bounds__(256) void k_gemm(const ushort_t* __restrict__ Aop0,
                                              const ushort_t* __restrict__ Wall,
                                              const float* __restrict__ bias,
                                              const int* __restrict__ blk2e,
                                              int K, int N,
                                              ushort_t* __restrict__ hout,
                                              float* __restrict__ outp,
                                              const int* __restrict__ row2tok,
                                              const float* __restrict__ roww) {
  int e = blk2e[blockIdx.y];
  if (e < 0) return;
  int rb = blockIdx.y, nb = blockIdx.x;
  int Kslice = K / gridDim.z;
  int kbase = blockIdx.z * Kslice;
  const ushort_t* Aop = Aop0 + (size_t)rb * 128 * K + kbase;
  const ushort_t* Bop = Wall + (size_t)e * N * K + (size_t)nb * 128 * K + kbase;
  __shared__ ushort_t As[8192], Bs[8192];   // 128 x 64 bf16 each (16 KB x2)
  int tid = threadIdx.x, lane = tid & 63, wv = tid >> 6;
  int l15 = lane & 15, q = lane >> 4;
  int wm = (wv & 1) << 6, wn = (wv >> 1) << 6;
  floatx4 acc[4][4];
#pragma unroll
  for (int i = 0; i < 4; i++)
#pragma unroll
    for (int j = 0; j < 4; j++) acc[i][j] = (floatx4){0.f, 0.f, 0.f, 0.f};
  // staging: chunk id c = r*256 + tid; row = c>>3 = r*32 + (tid>>3); cc = tid&7
  // swizzled source chunk = cc ^ (row&7); (row&7) == ((tid>>3)&7) since 32|r*32
  int row0 = tid >> 3;
  int swz  = (tid & 7) ^ (row0 & 7);
  size_t sa = (size_t)row0 * K + (size_t)(swz << 3);
  int ldsoff = wv * 512;   // ushorts; wave-uniform dest base
  int ksteps = Kslice >> 6;
  for (int ks = 0; ks < ksteps; ++ks) {
    const ushort_t* Ak = Aop + ks * 64;
    const ushort_t* Bk = Bop + ks * 64;
#pragma unroll
    for (int r = 0; r < 4; ++r) {
      stage16(Ak + sa + (size_t)(r * 32) * K, As + r * 2048 + ldsoff);
      stage16(Bk + sa + (size_t)(r * 32) * K, Bs + r * 2048 + ldsoff);
    }
    __syncthreads();   // drains vmcnt (global_load_lds) + barrier
#pragma unroll
    for (int s = 0; s < 2; ++s) {
      int cw = (s << 2) + q;
      shortx8 af[4], bfv[4];
#pragma unroll
      for (int i = 0; i < 4; i++) {
        int row = wm + i * 16 + l15;
        af[i] = *(const shortx8*)(As + (row << 6) + ((cw ^ (row & 7)) << 3));
      }
#pragma unroll
      for (int j = 0; j < 4; j++) {
        int row = wn + j * 16 + l15;
        bfv[j] = *(const shortx8*)(Bs + (row << 6) + ((cw ^ (row & 7)) << 3));
      }
#pragma unroll
      for (int i = 0; i < 4; i++)
#pragma unroll
        for (int j = 0; j < 4; j++)
          acc[i][j] = __builtin_amdgcn_mfma_f32_16x16x32_bf16(af[i], bfv[j], acc[i][j], 0, 0, 0);
    }
    __syncthreads();
  }
  const float* be = bias + (size_t)e * N + (size_t)nb * 128;
  if (hout) {
    ushort_t* hp = hout + (size_t)(rb * 128) * N + nb * 128;
#pragma unroll
    for (int j = 0; j < 4; j++) {
      int n = wn + j * 16 + l15;
      float bv = be[n];
#pragma unroll
      for (int i = 0; i < 4; i++)
#pragma unroll
        for (int r = 0; r < 4; r++) {
          int m = wm + i * 16 + (q << 2) + r;          // D row = quad*4 + reg
          hp[(size_t)m * N + n] = f2bf(acc[i][j][r] + bv);
        }
    }
  } else {
    bool addb = (blockIdx.z == 0);
#pragma unroll
    for (int j = 0; j < 4; j++) {
      int n = wn + j * 16 + l15;
      float bv = addb ? be[n] : 0.f;
#pragma unroll
      for (int i = 0; i < 4; i++)
#pragma unroll
        for (int r = 0; r < 4; r++) {
          int m = wm + i * 16 + (q << 2) + r;
          int grow = rb * 128 + m;
          int tok = row2tok[grow];
          if (tok >= 0) {
            float v = (acc[i][j][r] + bv) * roww[grow];
            atomicAdd(outp + (size_t)tok * 1024 + nb * 128 + n, v);
          }
        }
    }
  }
}

// ============================================================================
extern "C" void kernel_launch(void* const* d_in, const int* in_sizes, int n_in,
                              void* d_out, int out_size, void* d_ws, size_t ws_size,
                              hipStream_t stream) {
  (void)in_sizes; (void)n_in; (void)out_size; (void)ws_size;
  const float* x      = (const float*)d_in[0];
  const float* Wp     = (const float*)d_in[1];
  const float* bp     = (const float*)d_in[2];
  const float* sim    = (const float*)d_in[3];
  const float* temp   = (const float*)d_in[4];
  const float* A      = (const float*)d_in[5];
  const float* a_bias = (const float*)d_in[6];
  const float* Bw     = (const float*)d_in[7];
  const float* b_bias = (const float*)d_in[8];
  float* out = (float*)d_out;

  char* ws = (char*)d_ws;
  ushort_t* Abf    = (ushort_t*)(ws);                     //  67,108,864 B
  ushort_t* Bbf    = (ushort_t*)(ws + 67108864);          //  67,108,864 B
  ushort_t* xg     = (ushort_t*)(ws + 134217728);         //  19,136,512 B
  ushort_t* h      = (ushort_t*)(ws + 153354240);         //  76,546,048 B
  float*    proj   = (float*)   (ws + 229900288);         //   4,194,304 B
  int*      topi   = (int*)     (ws + 234094592);
  float*    wslot  = (float*)   (ws + 234127360);
  float*    swsum  = (float*)   (ws + 234160128);
  int*      row2tok= (int*)     (ws + 234176512);
  float*    roww   = (float*)   (ws + 234213888);
  int*      counts = (int*)     (ws + 234251264);
  int*      cursor = (int*)     (ws + 234251296);
  int*      offsets= (int*)     (ws + 234251328);
  int*      blk2e  = (int*)     (ws + 234251392);
  float*    fracs  = (float*)   (ws + 234251712);

  k_cvt<<<32768, 256, 0, stream>>>(A,  Abf, 8388608);
  k_cvt<<<32768, 256, 0, stream>>>(Bw, Bbf, 8388608);
  k_small_init<<<37, 256, 0, stream>>>(counts, cursor, fracs, row2tok);
  k_proj<<<256, 256, 0, stream>>>(x, Wp, bp, proj);
  k_gate<<<32, 128, 0, stream>>>(proj, sim, temp, topi, wslot, swsum, fracs, counts);
  k_scan<<<1, 128, 0, stream>>>(counts, fracs, offsets, blk2e, out + 4194304);
  k_assign<<<32, 256, 0, stream>>>(topi, wslot, offsets, cursor, row2tok, roww);
  k_gather<<<ROWS_PAD, 64, 0, stream>>>(x, row2tok, xg);
  k_init_out<<<4096, 256, 0, stream>>>(x, swsum, out);
  // GEMM1: h[r][j] = xg[r] . A_e[j] + a_bias  (K=1024, N=4096)
  k_gemm<<<dim3(32, MBLK, 1), 256, 0, stream>>>(xg, Abf, a_bias, blk2e, 1024, 4096,
                                                h, nullptr, nullptr, nullptr);
  // GEMM2: f[r][i] = h[r] . B_e[i] + b_bias; out[tok] += roww * f  (K=4096, N=1024, split-K x4)
  k_gemm<<<dim3(8, MBLK, 4), 256, 0, stream>>>(h, Bbf, b_bias, blk2e, 4096, 1024,
                                               nullptr, out, row2tok, roww);
}

// Round 3
// 808.765 us; speedup vs baseline: 1.0773x; 1.0601x over previous
//
#include <hip/hip_runtime.h>
#include <stdint.h>

// ============================================================================
// MoE adapter layer, sparse top-2 dispatch, bf16 MFMA expert GEMMs.
// R3: K-loop restructured -- register prefetch (distance 1) + single-buffer
//     LDS. global_load_lds dropped: its vmcnt(0)-at-barrier drain serialized
//     all co-resident blocks (R1->R2: 4x blocks, 0 bank conflicts => zero
//     gain, MfmaUtil pinned at 10.7%). Now global latency overlaps compute;
//     barriers only order LDS.
// Gating kept entirely fp32 (top-k decision boundaries are flip-sensitive).
// ============================================================================

typedef __attribute__((ext_vector_type(4))) float floatx4;
typedef __attribute__((ext_vector_type(8))) short shortx8;
typedef unsigned short ushort_t;

#define T_TOKENS 4096
#define D_DIM    1024
#define E_EXP    8
#define H_DIM    4096
#define P_DIM    256
#define ROWS_PAD 9344   // 8192 rows + per-expert 128-padding (max 9208) + slack
#define MBLK     73     // ROWS_PAD / 128

__device__ __forceinline__ ushort_t f2bf(float f) {
  union { float f; unsigned int u; } c; c.f = f;
  unsigned int u = c.u;
  unsigned int r = u + 0x7FFFu + ((u >> 16) & 1u);  // RNE
  return (ushort_t)(r >> 16);
}

// ---------------------------------------------------------------- convert
__global__ __launch_bounds__(256) void k_cvt(const float* __restrict__ src,
                                             ushort_t* __restrict__ dst, int n4) {
  int g = blockIdx.x * 256 + threadIdx.x;
  if (g >= n4) return;
  floatx4 v = ((const floatx4*)src)[g];
  ushort4 o; o.x = f2bf(v.x); o.y = f2bf(v.y); o.z = f2bf(v.z); o.w = f2bf(v.w);
  ((ushort4*)dst)[g] = o;
}

// ---------------------------------------------------------------- small init
__global__ __launch_bounds__(256) void k_small_init(int* counts, int* cursor,
                                                    float* frac_sum, int* row2tok) {
  int g = blockIdx.x * 256 + threadIdx.x;
  if (g < 8) { counts[g] = 0; cursor[g] = 0; frac_sum[g] = 0.f; }
  if (g < ROWS_PAD) row2tok[g] = -1;
}

// ---------------------------------------------------------------- proj = x @ Wp^T + bp   (fp32)
__global__ __launch_bounds__(256) void k_proj(const float* __restrict__ x,
                                              const float* __restrict__ Wp,
                                              const float* __restrict__ bp,
                                              float* __restrict__ proj) {
  __shared__ float Wc[256 * 36];
  __shared__ float Xc[16 * 36];
  int tid = threadIdx.x;
  int t0 = blockIdx.x * 16;
  int cg = tid & 31, tg = tid >> 5;
  floatx4 acc[2][8];
#pragma unroll
  for (int a = 0; a < 2; a++)
#pragma unroll
    for (int b = 0; b < 8; b++) acc[a][b] = (floatx4){0.f, 0.f, 0.f, 0.f};
  for (int kc = 0; kc < 32; ++kc) {
    int k0 = kc * 32;
    __syncthreads();
#pragma unroll
    for (int it = 0; it < 8; ++it) {
      int f = it * 256 + tid;
      int j = f >> 3, kk = (f & 7) << 2;
      floatx4 v = *(const floatx4*)(Wp + j * 1024 + k0 + kk);
      *(floatx4*)(Wc + j * 36 + kk) = v;
    }
    if (tid < 128) {
      int t = tid >> 3, kk = (tid & 7) << 2;
      floatx4 v = *(const floatx4*)(x + (size_t)(t0 + t) * 1024 + k0 + kk);
      *(floatx4*)(Xc + t * 36 + kk) = v;
    }
    __syncthreads();
#pragma unroll
    for (int k4 = 0; k4 < 8; ++k4) {
      floatx4 xv[2], wv[8];
#pragma unroll
      for (int tt = 0; tt < 2; tt++) xv[tt] = *(floatx4*)(Xc + (tg * 2 + tt) * 36 + k4 * 4);
#pragma unroll
      for (int jj = 0; jj < 8; jj++) wv[jj] = *(floatx4*)(Wc + (cg + jj * 32) * 36 + k4 * 4);
#pragma unroll
      for (int tt = 0; tt < 2; tt++)
#pragma unroll
        for (int jj = 0; jj < 8; jj++) acc[tt][jj] += xv[tt] * wv[jj];
    }
  }
#pragma unroll
  for (int tt = 0; tt < 2; tt++)
#pragma unroll
    for (int jj = 0; jj < 8; jj++) {
      floatx4 a = acc[tt][jj];
      float s = (a.x + a.y) + (a.z + a.w);
      int t = t0 + tg * 2 + tt, j = cg + jj * 32;
      proj[t * 256 + j] = s + bp[j];
    }
}

// ---------------------------------------------------------------- gate
__global__ __launch_bounds__(128) void k_gate(const float* __restrict__ proj,
                                              const float* __restrict__ sim,
                                              const float* __restrict__ temp,
                                              int* __restrict__ topi, float* __restrict__ wslot,
                                              float* __restrict__ swsum,
                                              float* __restrict__ frac_sum, int* __restrict__ counts) {
  __shared__ float simT[8][256];
  __shared__ float snorm[8];
  __shared__ float fracs[8];
  __shared__ int cnts[8];
  int tid = threadIdx.x;
  for (int i = tid; i < 2048; i += 128) { int p = i >> 3, e = i & 7; simT[e][p] = sim[i]; }
  if (tid < 8) { fracs[tid] = 0.f; cnts[tid] = 0; }
  __syncthreads();
  if (tid < 8) {
    float s = 0.f;
    for (int p = 0; p < 256; p++) { float v = simT[tid][p]; s += v * v; }
    snorm[tid] = fmaxf(sqrtf(s), 1e-12f);
  }
  __syncthreads();
  int t = blockIdx.x * 128 + tid;
  floatx4 n4 = (floatx4){0.f, 0.f, 0.f, 0.f};
  floatx4 d4[8];
#pragma unroll
  for (int e = 0; e < 8; e++) d4[e] = (floatx4){0.f, 0.f, 0.f, 0.f};
  const floatx4* pr = (const floatx4*)(proj + t * 256);
  for (int k4 = 0; k4 < 64; ++k4) {
    floatx4 p = pr[k4];
    n4 += p * p;
#pragma unroll
    for (int e = 0; e < 8; e++) d4[e] += p * *(const floatx4*)(&simT[e][k4 * 4]);
  }
  float nrm = fmaxf(sqrtf((n4.x + n4.y) + (n4.z + n4.w)), 1e-12f);
  float scale = expf(fminf(temp[0], 4.6051701859880914f));  // log(100)
  float pe[8];
  float mx = -1e30f;
#pragma unroll
  for (int e = 0; e < 8; e++) {
    float d = (d4[e].x + d4[e].y) + (d4[e].z + d4[e].w);
    pe[e] = d / (nrm * snorm[e]) * scale;
    mx = fmaxf(mx, pe[e]);
  }
  float sum = 0.f;
#pragma unroll
  for (int e = 0; e < 8; e++) { pe[e] = expf(pe[e] - mx); sum += pe[e]; }
#pragma unroll
  for (int e = 0; e < 8; e++) pe[e] /= sum;
  int i0 = 0;
#pragma unroll
  for (int e = 1; e < 8; e++) if (pe[e] > pe[i0]) i0 = e;
  int i1 = (i0 == 0) ? 1 : 0;
#pragma unroll
  for (int e = 0; e < 8; e++) if (e != i1 && e != i0 && pe[e] > pe[i1]) i1 = e;
  float v0 = pe[i0], v1 = pe[i1];
  float s2 = v0 + v1 + 1e-8f;
  float w0 = v0 / s2, w1 = v1 / s2;
  topi[t * 2] = i0; topi[t * 2 + 1] = i1;
  wslot[t * 2] = w0; wslot[t * 2 + 1] = w1;
  swsum[t] = w0 + w1;
#pragma unroll
  for (int e = 0; e < 8; e++) atomicAdd(&fracs[e], pe[e]);
  atomicAdd(&cnts[i0], 1); atomicAdd(&cnts[i1], 1);
  __syncthreads();
  if (tid < 8) { atomicAdd(&frac_sum[tid], fracs[tid]); atomicAdd(&counts[tid], cnts[tid]); }
}

// ---------------------------------------------------------------- scan
__global__ void k_scan(const int* __restrict__ counts, const float* __restrict__ frac_sum,
                       int* __restrict__ offsets, int* __restrict__ blk2e,
                       float* __restrict__ out_tail) {
  __shared__ int offs[9];
  if (threadIdx.x == 0) {
    int off = 0;
    for (int e = 0; e < 8; e++) { offs[e] = off; off += ((counts[e] + 127) >> 7) << 7; }
    offs[8] = off;
    for (int e = 0; e < 9; e++) offsets[e] = offs[e];
    float aux = 0.f;
    for (int e = 0; e < 8; e++) { float fr = frac_sum[e] / 4096.f; aux += (fr - 0.125f) * (fr - 0.125f); }
    out_tail[0] = aux;
  }
  __syncthreads();
  int tid = threadIdx.x;
  if (tid < MBLK) {
    int r = tid * 128, e = -1;
    for (int q = 0; q < 8; q++) if (r >= offs[q] && r < offs[q + 1]) e = q;
    blk2e[tid] = e;
  }
  if (tid < 8) {
    out_tail[1 + tid] = frac_sum[tid] / 4096.f;
    out_tail[9 + tid] = (float)counts[tid];
  }
}

// ---------------------------------------------------------------- assign rows
__global__ __launch_bounds__(256) void k_assign(const int* __restrict__ topi,
                                                const float* __restrict__ wslot,
                                                const int* __restrict__ offsets,
                                                int* __restrict__ cursor,
                                                int* __restrict__ row2tok, float* __restrict__ roww) {
  int g = blockIdx.x * 256 + threadIdx.x;
  if (g >= 8192) return;
  int t = g >> 1;
  int e = topi[g];
  int pos = atomicAdd(&cursor[e], 1);
  int r = offsets[e] + pos;
  row2tok[r] = t;
  roww[r] = wslot[g];
}

// ---------------------------------------------------------------- gather x rows -> bf16
__global__ __launch_bounds__(64) void k_gather(const float* __restrict__ x,
                                               const int* __restrict__ row2tok,
                                               ushort_t* __restrict__ xg) {
  int r = blockIdx.x;
  int t = row2tok[r];
  ushort4* dst = (ushort4*)(xg + (size_t)r * 1024);
  if (t < 0) {
    ushort4 z; z.x = z.y = z.z = z.w = 0;
    for (int i = threadIdx.x; i < 256; i += 64) dst[i] = z;
  } else {
    const floatx4* src = (const floatx4*)(x + (size_t)t * 1024);
    for (int i = threadIdx.x; i < 256; i += 64) {
      floatx4 v = src[i];
      ushort4 o; o.x = f2bf(v.x); o.y = f2bf(v.y); o.z = f2bf(v.z); o.w = f2bf(v.w);
      dst[i] = o;
    }
  }
}

// ---------------------------------------------------------------- out = (w0+w1) * x
__global__ __launch_bounds__(256) void k_init_out(const float* __restrict__ x,
                                                  const float* __restrict__ swsum,
                                                  float* __restrict__ out) {
  int g = blockIdx.x * 256 + threadIdx.x;
  float s = swsum[g >> 8];
  floatx4 v = ((const floatx4*)x)[g];
  ((floatx4*)out)[g] = v * s;
}

// ---------------------------------------------------------------- bf16 MFMA GEMM (NT), 128x128 tile, BK=64
// Register-prefetch pipeline: global->VGPR loads for step k+1 issue before
// compute of step k; ds_write at top of step k+1 takes the vmcnt wait AFTER
// compute has covered the latency. Single 32 KB LDS buffer; 2 barriers/step,
// neither waits on global memory.
// LDS chunk swizzle: 16B chunk at (row, c) stored at c ^ (row & 7).
// mode 1 (hout!=0): h = Aop @ W^T + bias -> bf16
// mode 2 (hout==0): f = Aop @ W^T (+bias iff z==0); atomicAdd(out[tok], roww*f)
__global__ __launch_bounds__(256) void k_gemm(const ushort_t* __restrict__ Aop0,
                                              const ushort_t* __restrict__ Wall,
                                              const float* __restrict__ bias,
                                              const int* __restrict__ blk2e,
                                              int K, int N,
                                              ushort_t* __restrict__ hout,
                                              float* __restrict__ outp,
                                              const int* __restrict__ row2tok,
                                              const float* __restrict__ roww) {
  int e = blk2e[blockIdx.y];
  if (e < 0) return;
  int rb = blockIdx.y, nb = blockIdx.x;
  int Kslice = K / gridDim.z;
  int kbase = blockIdx.z * Kslice;
  const ushort_t* Aop = Aop0 + (size_t)rb * 128 * K + kbase;
  const ushort_t* Bop = Wall + (size_t)e * N * K + (size_t)nb * 128 * K + kbase;
  __shared__ ushort_t As[8192], Bs[8192];   // 128 rows x 64 cols bf16 each
  int tid = threadIdx.x, lane = tid & 63, wv = tid >> 6;
  int l15 = lane & 15, q = lane >> 4;
  int wm = (wv & 1) << 6, wn = (wv >> 1) << 6;
  floatx4 acc[4][4];
#pragma unroll
  for (int i = 0; i < 4; i++)
#pragma unroll
    for (int j = 0; j < 4; j++) acc[i][j] = (floatx4){0.f, 0.f, 0.f, 0.f};

  // staging addressing: chunk c = r*256 + tid  (r=0..3), row = c>>3 (128 rows),
  // col-chunk = c&7. Global: row*K + colc*8 (coalesced 16B/lane).
  // LDS: row*64 + ((colc ^ (row&7))<<3).  row&7 == (tid>>3)&7 (r*32 = 0 mod 8).
  int row0 = tid >> 3, colc = tid & 7;
  size_t ga = (size_t)row0 * K + (size_t)(colc << 3);
  int wa = (row0 << 6) + ((colc ^ (row0 & 7)) << 3);
  int ksteps = Kslice >> 6;

  shortx8 rA[4], rB[4];
  // prologue: load step 0
#pragma unroll
  for (int r = 0; r < 4; ++r) {
    rA[r] = *(const shortx8*)(Aop + ga + (size_t)(r * 32) * K);
    rB[r] = *(const shortx8*)(Bop + ga + (size_t)(r * 32) * K);
  }
  for (int ks = 0; ks < ksteps; ++ks) {
    // commit staged regs to LDS (vmcnt wait lands here, after prior compute)
#pragma unroll
    for (int r = 0; r < 4; ++r) {
      *(shortx8*)(As + wa + r * 2048) = rA[r];
      *(shortx8*)(Bs + wa + r * 2048) = rB[r];
    }
    __syncthreads();
    // issue next step's global loads (clamped re-load on last step; unused)
    int kn = (ks + 1 < ksteps) ? (ks + 1) : ks;
    const ushort_t* An = Aop + kn * 64;
    const ushort_t* Bn = Bop + kn * 64;
#pragma unroll
    for (int r = 0; r < 4; ++r) {
      rA[r] = *(const shortx8*)(An + ga + (size_t)(r * 32) * K);
      rB[r] = *(const shortx8*)(Bn + ga + (size_t)(r * 32) * K);
    }
    // compute current step from LDS
#pragma unroll
    for (int s = 0; s < 2; ++s) {
      int cw = (s << 2) + q;
      shortx8 af[4], bfv[4];
#pragma unroll
      for (int i = 0; i < 4; i++) {
        int row = wm + i * 16 + l15;
        af[i] = *(const shortx8*)(As + (row << 6) + ((cw ^ (row & 7)) << 3));
      }
#pragma unroll
      for (int j = 0; j < 4; j++) {
        int row = wn + j * 16 + l15;
        bfv[j] = *(const shortx8*)(Bs + (row << 6) + ((cw ^ (row & 7)) << 3));
      }
#pragma unroll
      for (int i = 0; i < 4; i++)
#pragma unroll
        for (int j = 0; j < 4; j++)
          acc[i][j] = __builtin_amdgcn_mfma_f32_16x16x32_bf16(af[i], bfv[j], acc[i][j], 0, 0, 0);
    }
    __syncthreads();   // reads done before next ds_write overwrites
  }
  const float* be = bias + (size_t)e * N + (size_t)nb * 128;
  if (hout) {
    ushort_t* hp = hout + (size_t)(rb * 128) * N + nb * 128;
#pragma unroll
    for (int j = 0; j < 4; j++) {
      int n = wn + j * 16 + l15;
      float bv = be[n];
#pragma unroll
      for (int i = 0; i < 4; i++)
#pragma unroll
        for (int r = 0; r < 4; r++) {
          int m = wm + i * 16 + (q << 2) + r;          // D row = quad*4 + reg
          hp[(size_t)m * N + n] = f2bf(acc[i][j][r] + bv);
        }
    }
  } else {
    bool addb = (blockIdx.z == 0);
#pragma unroll
    for (int j = 0; j < 4; j++) {
      int n = wn + j * 16 + l15;
      float bv = addb ? be[n] : 0.f;
#pragma unroll
      for (int i = 0; i < 4; i++)
#pragma unroll
        for (int r = 0; r < 4; r++) {
          int m = wm + i * 16 + (q << 2) + r;
          int grow = rb * 128 + m;
          int tok = row2tok[grow];
          if (tok >= 0) {
            float v = (acc[i][j][r] + bv) * roww[grow];
            atomicAdd(outp + (size_t)tok * 1024 + nb * 128 + n, v);
          }
        }
    }
  }
}

// ============================================================================
extern "C" void kernel_launch(void* const* d_in, const int* in_sizes, int n_in,
                              void* d_out, int out_size, void* d_ws, size_t ws_size,
                              hipStream_t stream) {
  (void)in_sizes; (void)n_in; (void)out_size; (void)ws_size;
  const float* x      = (const float*)d_in[0];
  const float* Wp     = (const float*)d_in[1];
  const float* bp     = (const float*)d_in[2];
  const float* sim    = (const float*)d_in[3];
  const float* temp   = (const float*)d_in[4];
  const float* A      = (const float*)d_in[5];
  const float* a_bias = (const float*)d_in[6];
  const float* Bw     = (const float*)d_in[7];
  const float* b_bias = (const float*)d_in[8];
  float* out = (float*)d_out;

  char* ws = (char*)d_ws;
  ushort_t* Abf    = (ushort_t*)(ws);                     //  67,108,864 B
  ushort_t* Bbf    = (ushort_t*)(ws + 67108864);          //  67,108,864 B
  ushort_t* xg     = (ushort_t*)(ws + 134217728);         //  19,136,512 B
  ushort_t* h      = (ushort_t*)(ws + 153354240);         //  76,546,048 B
  float*    proj   = (float*)   (ws + 229900288);         //   4,194,304 B
  int*      topi   = (int*)     (ws + 234094592);
  float*    wslot  = (float*)   (ws + 234127360);
  float*    swsum  = (float*)   (ws + 234160128);
  int*      row2tok= (int*)     (ws + 234176512);
  float*    roww   = (float*)   (ws + 234213888);
  int*      counts = (int*)     (ws + 234251264);
  int*      cursor = (int*)     (ws + 234251296);
  int*      offsets= (int*)     (ws + 234251328);
  int*      blk2e  = (int*)     (ws + 234251392);
  float*    fracs  = (float*)   (ws + 234251712);

  k_cvt<<<32768, 256, 0, stream>>>(A,  Abf, 8388608);
  k_cvt<<<32768, 256, 0, stream>>>(Bw, Bbf, 8388608);
  k_small_init<<<37, 256, 0, stream>>>(counts, cursor, fracs, row2tok);
  k_proj<<<256, 256, 0, stream>>>(x, Wp, bp, proj);
  k_gate<<<32, 128, 0, stream>>>(proj, sim, temp, topi, wslot, swsum, fracs, counts);
  k_scan<<<1, 128, 0, stream>>>(counts, fracs, offsets, blk2e, out + 4194304);
  k_assign<<<32, 256, 0, stream>>>(topi, wslot, offsets, cursor, row2tok, roww);
  k_gather<<<ROWS_PAD, 64, 0, stream>>>(x, row2tok, xg);
  k_init_out<<<4096, 256, 0, stream>>>(x, swsum, out);
  // GEMM1: h[r][j] = xg[r] . A_e[j] + a_bias  (K=1024, N=4096)
  k_gemm<<<dim3(32, MBLK, 1), 256, 0, stream>>>(xg, Abf, a_bias, blk2e, 1024, 4096,
                                                h, nullptr, nullptr, nullptr);
  // GEMM2: f = h . B_e^T + b_bias; out[tok] += roww * f  (K=4096, N=1024, split-K x2)
  k_gemm<<<dim3(8, MBLK, 2), 256, 0, stream>>>(h, Bbf, b_bias, blk2e, 4096, 1024,
                                               nullptr, out, row2tok, roww);
}